// Round 4
// baseline (6395.309 us; speedup 1.0000x reference)
//
#include <hip/hip_runtime.h>

#define EPS 1e-5f

__device__ __forceinline__ float logsig(float z) {
    return fminf(z, 0.0f) - log1pf(__expf(-fabsf(z)));
}

// One block = one sequence. 512 threads = 8 waves.
// Head h = wave&3; k-half kh = wave>>2 (kh0 holds S rows 0..31, kh1 rows 32..63).
// PSTRIDE==1  : intra pass (seq over q, SLEN=128); PSTRIDE==128: inter pass (SLEN=256)
// Empirical RA law on this backend (R0/R1/R2): VGPR cap = 2048/(2*waves_per_wg)
// regardless of LDS or waves_per_eu attributes -> 512 thr = 128 regs. Stay at 512.
// R3: slab double-buffer + reg prefetch (T14), wave-parallel LN, Ats/gdec overlay.
// R4: fuse V+R projections (col[17] read once, ar[16] held through F, G = pure
//     silu apply) and defer gate exps (hold run[16], not erunp/erunm[32]) to
//     free 16 regs across the C stage for load pipelining.
template<int SLEN, int PSTRIDE>
__global__ __launch_bounds__(512)
__attribute__((amdgpu_waves_per_eu(2, 2)))
void gla_pass(const float* __restrict__ src, float* __restrict__ out,
              const float* __restrict__ gamma, const float* __restrict__ beta,
              const float* __restrict__ Wq, const float* __restrict__ Wk,
              const float* __restrict__ Wv, const float* __restrict__ Wg1,
              const float* __restrict__ Wg2, const float* __restrict__ Wr,
              const float* __restrict__ gn, const float* __restrict__ Wo,
              const float* __restrict__ ctw, const float* __restrict__ ctb)
{
    constexpr int NC = SLEN / 32;
    constexpr int L  = SLEN - 1;

    __shared__ __align__(16) float sxA[64][36];   // slab buffer A (33 cols used)
    __shared__ __align__(16) float sxB[64][36];   // slab buffer B
    __shared__ __align__(16) float sxr[64][32];   // raw slab (residual source)
    __shared__ __align__(16) float qf[32][256];   // q*Dk^-0.5 * exp(gc)
    __shared__ __align__(16) float kf[32][256];   // k * exp(-gc)
    __shared__ __align__(16) float voc[32][256];  // v -> oe1 partial -> o -> o*silu(r)
    __shared__ __align__(16) float uni[4608];     // Ats[4][32][36] OVERLAID with gdec[32][132]
    __shared__ __align__(16) float fw1t[32][36];  // (f @ Wg1)^T : fw1t[m][t]
    __shared__ __align__(16) float gprevs[128];   // deconv carry row
    __shared__ float egl[256];                    // exp(chunk-total gate)
    __shared__ float sgam[64], sbet[64];
    __shared__ float smu[33], sinv[33];
    __shared__ float gcarry[256];                 // gate cumsum carry (t=0..15 total)

    float* const Ats  = uni;          // h*1152 + t*36 + s      (live F1 -> F2b)
    float* const gdec = uni;          // row*132 + c            (live H -> I; Ats dead)

    const int tid  = threadIdx.x;
    const int lane = tid & 63;
    const int wv   = tid >> 6;        // 0..7
    const int h    = wv & 3;          // head
    const int kh   = wv >> 2;         // k-half
    const int d    = tid & 255;       // column for t-split stages
    const int th   = (tid >> 8) & 1;  // t-half (rows th*16 .. th*16+15); th == kh
    const int n    = blockIdx.x;

    int b, fixedoff;
    if constexpr (PSTRIDE == 1) { b = n >> 8; fixedoff = (n & 255) * 128; }
    else                        { b = n >> 7; fixedoff = (n & 127); }
    const int cbase = (b * 64) * 32768 + fixedoff;

    if (tid < 64)  { sgam[tid] = gamma[tid]; sbet[tid] = beta[tid]; }
    if (tid < 128) gprevs[tid] = 0.0f;

    float S[32];
    #pragma unroll
    for (int k = 0; k < 32; ++k) S[k] = 0.0f;

    const float gnv  = gn[h * 64 + lane];
    const float bias = ctb[lane];

    // ---- prologue: chunk-0 slab -> sxA (raw) ----
    #pragma unroll
    for (int k = 0; k < 5; ++k) {
        int idx = tid + k * 512;
        if (idx < 64 * 33) {
            int cc = idx / 33, i = idx - cc * 33;
            sxA[cc][i] = src[cbase + cc * 32768 + i * PSTRIDE];
        }
    }

    for (int ch = 0; ch < NC; ++ch) {
        const int l0 = ch * 32;
        float (* const cur)[36] = (ch & 1) ? sxB : sxA;
        float (* const nxt)[36] = (ch & 1) ? sxA : sxB;
        __syncthreads();              // cur(ch) raw ready (prologue or prefetch)

        // ---- A': issue next-chunk slab loads into registers (write to nxt later) ----
        float pre[5];
        const bool pf = (ch + 1 < NC);
        if (pf) {
            const int l0n = l0 + 32;
            #pragma unroll
            for (int k = 0; k < 5; ++k) {
                int idx = tid + k * 512;
                if (idx < 64 * 33) {
                    int cc = idx / 33, i = idx - cc * 33;
                    int p  = l0n + i; if (p > SLEN - 1) p = SLEN - 1;
                    pre[k] = src[cbase + cc * 32768 + p * PSTRIDE];
                }
            }
        }

        // ---- B1: per-column LN stats, wave-parallel (8 waves x shfl tree) ----
        for (int col = wv; col < 33; col += 8) {
            float x = cur[lane][col];
            float s1 = x, s2 = x * x;
            #pragma unroll
            for (int off = 32; off > 0; off >>= 1) {
                s1 += __shfl_xor(s1, off, 64);
                s2 += __shfl_xor(s2, off, 64);
            }
            if (lane == 0) {
                float mu  = s1 * (1.0f / 64.0f);
                float var = s2 * (1.0f / 64.0f) - mu * mu;
                smu[col]  = mu;
                sinv[col] = rsqrtf(fmaxf(var, 0.0f) + EPS);
            }
        }
        __syncthreads();

        // ---- B2: normalize in place, raw copy to sxr fused ----
        #pragma unroll
        for (int k = 0; k < 5; ++k) {
            int idx = tid + k * 512;
            if (idx < 64 * 33) {
                int cc = idx / 33, i = idx - cc * 33;
                float x = cur[cc][i];
                if (i < 32) sxr[cc][i] = x;
                cur[cc][i] = (x - smu[i]) * sinv[i] * sgam[cc] + sbet[cc];
            }
        }
        __syncthreads();

        // ---- gate p1: fw1t[m][t] ----
        {
            const int m = tid & 31, tg2 = tid >> 5;   // tg2 in [0,16)
            float a0 = 0.0f, a1 = 0.0f;
            #pragma unroll 2
            for (int cc = 0; cc < 64; ++cc) {
                const float w0 = Wg1[(2*cc)*32 + m], w1 = Wg1[(2*cc+1)*32 + m];
                a0 += cur[cc][tg2]      * w0 + cur[cc][tg2 + 1]  * w1;
                a1 += cur[cc][tg2 + 16] * w0 + cur[cc][tg2 + 17] * w1;
            }
            fw1t[m][tg2] = a0; fw1t[m][tg2 + 16] = a1;
        }
        __syncthreads();

        // ---- gate p2: per (col d, t-half) cumsum with carry -> run[16] ----
        float rn[16];                 // log-gate cumsum; exps deferred to stores
        {
            const int t0 = th * 16;
            float acc2[16];
            #pragma unroll
            for (int t = 0; t < 16; ++t) acc2[t] = 0.0f;
            for (int mm = 0; mm < 32; ++mm) {
                const float w = Wg2[mm * 256 + d];
                #pragma unroll
                for (int i = 0; i < 4; ++i) {
                    float4 f4 = *(const float4*)&fw1t[mm][t0 + 4 * i];
                    acc2[4*i+0] += f4.x * w; acc2[4*i+1] += f4.y * w;
                    acc2[4*i+2] += f4.z * w; acc2[4*i+3] += f4.w * w;
                }
            }
            float r = 0.0f;
            #pragma unroll
            for (int t = 0; t < 16; ++t) {
                if ((l0 + t0 + t) < L) r += logsig(acc2[t]) * (1.0f / 32.0f);
                acc2[t] = r;                    // reuse as cumsum store
            }
            if (th == 0) gcarry[d] = r;
            __syncthreads();
            const float c = (th == 0) ? 0.0f : gcarry[d];
            #pragma unroll
            for (int t = 0; t < 16; ++t) rn[t] = c + acc2[t];
            if (th == 1) egl[d] = __expf(rn[15]);
        }

        // ---- A'': write prefetched slab into nxt (loads returned long ago;
        //          nxt is untouched until next chunk's loop-top barrier) ----
        if (pf) {
            #pragma unroll
            for (int k = 0; k < 5; ++k) {
                int idx = tid + k * 512;
                if (idx < 64 * 33) {
                    int cc = idx / 33, i = idx - cc * 33;
                    nxt[cc][i] = pre[k];
                }
            }
        }

        // ---- C1: q,k fused projection; gate exp folded at store ----
        {
            const int t0 = th * 16;
            float aq[16], ak[16];
            #pragma unroll
            for (int t = 0; t < 16; ++t) { aq[t] = 0.0f; ak[t] = 0.0f; }
            for (int cc = 0; cc < 64; ++cc) {
                float col[17];
                #pragma unroll
                for (int i = 0; i < 4; ++i) {
                    float4 c4 = *(const float4*)&cur[cc][t0 + 4 * i];
                    col[4*i] = c4.x; col[4*i+1] = c4.y; col[4*i+2] = c4.z; col[4*i+3] = c4.w;
                }
                col[16] = cur[cc][t0 + 16];
                const float wq0 = Wq[(2*cc)*256 + d], wq1 = Wq[(2*cc+1)*256 + d];
                const float wk0 = Wk[(2*cc)*256 + d], wk1 = Wk[(2*cc+1)*256 + d];
                #pragma unroll
                for (int t = 0; t < 16; ++t) {
                    aq[t] += col[t] * wq0 + col[t+1] * wq1;
                    ak[t] += col[t] * wk0 + col[t+1] * wk1;
                }
            }
            #pragma unroll
            for (int t = 0; t < 16; ++t) {
                bool valid = (l0 + t0 + t) < L;
                qf[t0 + t][d] = valid ? aq[t] * 0.125f * __expf(rn[t]) : 0.0f;
                kf[t0 + t][d] = valid ? ak[t] * __expf(-rn[t]) : 0.0f;
            }
        }
        // ---- C2: v,r fused projection (col read once); ar kept in regs for G ----
        float ar[16];
        {
            const int t0 = th * 16;
            float av[16];
            #pragma unroll
            for (int t = 0; t < 16; ++t) { av[t] = 0.0f; ar[t] = 0.0f; }
            #pragma unroll 2
            for (int cc = 0; cc < 64; ++cc) {
                float col[17];
                #pragma unroll
                for (int i = 0; i < 4; ++i) {
                    float4 c4 = *(const float4*)&cur[cc][t0 + 4 * i];
                    col[4*i] = c4.x; col[4*i+1] = c4.y; col[4*i+2] = c4.z; col[4*i+3] = c4.w;
                }
                col[16] = cur[cc][t0 + 16];
                const float wv0 = Wv[(2*cc)*256 + d], wv1 = Wv[(2*cc+1)*256 + d];
                const float wr0 = Wr[(2*cc)*256 + d], wr1 = Wr[(2*cc+1)*256 + d];
                #pragma unroll
                for (int t = 0; t < 16; ++t) {
                    av[t] += col[t] * wv0 + col[t+1] * wv1;
                    ar[t] += col[t] * wr0 + col[t+1] * wr1;
                }
            }
            #pragma unroll
            for (int t = 0; t < 16; ++t)
                voc[t0 + t][d] = ((l0 + t0 + t) < L) ? av[t] : 0.0f;
        }
        __syncthreads();

        // ---- F: attention; 2 waves per head ----
        const int base = h * 64;
        float vcol[32];
        #pragma unroll
        for (int t = 0; t < 32; ++t) vcol[t] = voc[t][base + lane];

        // F1: triangular scores, 128 lanes per head
        for (int pi = lane + 64 * kh; pi < 528; pi += 128) {
            float fpi = (float)pi;
            int t = (int)((sqrtf(8.0f * fpi + 1.0f) - 1.0f) * 0.5f);
            if (((t + 1) * (t + 2)) / 2 <= pi) ++t;
            if ((t * (t + 1)) / 2 > pi) --t;
            int s = pi - (t * (t + 1)) / 2;
            float a = 0.0f;
            #pragma unroll
            for (int ii = 0; ii < 16; ++ii) {
                int i = (ii + lane) & 15;
                float4 q4 = *(const float4*)&qf[t][base + 4 * i];
                float4 k4 = *(const float4*)&kf[s][base + 4 * i];
                a += q4.x*k4.x + q4.y*k4.y + q4.z*k4.z + q4.w*k4.w;
            }
            Ats[h * 1152 + t * 36 + s] = a;
        }
        __syncthreads();   // A: Ats ready; all vcol snapshots done (voc dead as v)

        // F2a: kh1 writes o_inter partial (vs pre-update S rows 32..63) into voc
        if (kh == 1) {
            #pragma unroll
            for (int t = 0; t < 32; ++t) {
                float oe = 0.0f;
                #pragma unroll
                for (int i = 0; i < 8; ++i) {
                    float4 q4 = *(const float4*)&qf[t][base + 32 + 4 * i];
                    oe += q4.x*S[4*i] + q4.y*S[4*i+1] + q4.z*S[4*i+2] + q4.w*S[4*i+3];
                }
                voc[t][base + lane] = oe;
            }
        }
        __syncthreads();   // B: oe1 partials in voc

        if (kh == 0) {
            // F2b: o = oe0 + oe1 + o_intra, RMS-norm, final o into voc
            #pragma unroll
            for (int t = 0; t < 32; ++t) {
                float ot = voc[t][base + lane];
                #pragma unroll
                for (int i = 0; i < 8; ++i) {
                    float4 q4 = *(const float4*)&qf[t][base + 4 * i];
                    ot += q4.x*S[4*i] + q4.y*S[4*i+1] + q4.z*S[4*i+2] + q4.w*S[4*i+3];
                }
                const float* arow = &Ats[h * 1152 + t * 36];
                #pragma unroll
                for (int s4 = 0; s4 + 4 <= t + 1; s4 += 4) {
                    float4 a4 = *(const float4*)&arow[s4];
                    ot += a4.x*vcol[s4] + a4.y*vcol[s4+1] + a4.z*vcol[s4+2] + a4.w*vcol[s4+3];
                }
                #pragma unroll
                for (int s = (t + 1) & ~3; s <= t; ++s) ot += arow[s] * vcol[s];
                float ss = ot * ot;
                #pragma unroll
                for (int off = 32; off > 0; off >>= 1) ss += __shfl_xor(ss, off, 64);
                voc[t][base + lane] = ot * rsqrtf(ss * (1.0f / 64.0f) + EPS) * gnv;
            }
        } else {
            // kh1: F4 state update rows 32..63 (overlaps kh0's F2b)
            const int kb = base + 32;
            #pragma unroll
            for (int i = 0; i < 8; ++i) {
                float s0 = 0.0f, s1 = 0.0f, s2 = 0.0f, s3 = 0.0f;
                #pragma unroll
                for (int t = 0; t < 32; ++t) {
                    float4 k4 = *(const float4*)&kf[t][kb + 4 * i];
                    const float vt = vcol[t];
                    s0 += k4.x * vt; s1 += k4.y * vt; s2 += k4.z * vt; s3 += k4.w * vt;
                }
                S[4*i+0] = egl[kb + 4*i+0] * (S[4*i+0] + s0);
                S[4*i+1] = egl[kb + 4*i+1] * (S[4*i+1] + s1);
                S[4*i+2] = egl[kb + 4*i+2] * (S[4*i+2] + s2);
                S[4*i+3] = egl[kb + 4*i+3] * (S[4*i+3] + s3);
            }
        }
        __syncthreads();   // C: final o in voc; kh0 may now update S

        if (kh == 0) {
            // F4 state update rows 0..31 (overlaps kh1's half of G)
            const int kb = base;
            #pragma unroll
            for (int i = 0; i < 8; ++i) {
                float s0 = 0.0f, s1 = 0.0f, s2 = 0.0f, s3 = 0.0f;
                #pragma unroll
                for (int t = 0; t < 32; ++t) {
                    float4 k4 = *(const float4*)&kf[t][kb + 4 * i];
                    const float vt = vcol[t];
                    s0 += k4.x * vt; s1 += k4.y * vt; s2 += k4.z * vt; s3 += k4.w * vt;
                }
                S[4*i+0] = egl[kb + 4*i+0] * (S[4*i+0] + s0);
                S[4*i+1] = egl[kb + 4*i+1] * (S[4*i+1] + s1);
                S[4*i+2] = egl[kb + 4*i+2] * (S[4*i+2] + s2);
                S[4*i+3] = egl[kb + 4*i+3] * (S[4*i+3] + s3);
            }
        }

        // ---- G: voc *= silu(r) (r held in regs from C2; no loads) ----
        {
            const int t0 = th * 16;
            #pragma unroll
            for (int t = 0; t < 16; ++t) {
                const float r = ar[t];
                voc[t0 + t][d] *= r / (1.0f + __expf(-r));
            }
        }
        __syncthreads();

        // ---- H: gdec = oc @ Wo ; thread = (m2 in [0,64), 2 cols, 4 rows) ----
        // (gdec overlays Ats: Ats last read was F2b, two barriers ago)
        {
            const int m2  = tid & 63;
            const int tg4 = tid >> 6;        // 0..7 -> rows tg4*4..+3
            float accA[4] = {0,0,0,0}, accB[4] = {0,0,0,0};
            for (int j = 0; j < 256; j += 4) {
                float wA0 = Wo[(j+0)*128 + m2],      wB0 = Wo[(j+0)*128 + m2 + 64];
                float wA1 = Wo[(j+1)*128 + m2],      wB1 = Wo[(j+1)*128 + m2 + 64];
                float wA2 = Wo[(j+2)*128 + m2],      wB2 = Wo[(j+2)*128 + m2 + 64];
                float wA3 = Wo[(j+3)*128 + m2],      wB3 = Wo[(j+3)*128 + m2 + 64];
                #pragma unroll
                for (int i = 0; i < 4; ++i) {
                    float4 o4 = *(const float4*)&voc[tg4 * 4 + i][j];
                    accA[i] += o4.x*wA0 + o4.y*wA1 + o4.z*wA2 + o4.w*wA3;
                    accB[i] += o4.x*wB0 + o4.y*wB1 + o4.z*wB2 + o4.w*wB3;
                }
            }
            #pragma unroll
            for (int i = 0; i < 4; ++i) {
                gdec[(tg4 * 4 + i) * 132 + m2]      = accA[i];
                gdec[(tg4 * 4 + i) * 132 + m2 + 64] = accB[i];
            }
        }
        __syncthreads();

        // ---- I: deconv1d (K=2) + bias + residual (from sxr) + store ----
        {
            const int o  = lane;
            const int pg = wv;               // 0..7 -> rows pg*4..+3
            const float2* ctw2 = (const float2*)ctw;   // [cin][o] -> (w_k0, w_k1)
            float acc4[4] = {0,0,0,0};
            for (int c4 = 0; c4 < 128; c4 += 4) {
                float2 w0 = ctw2[(c4+0)*64 + o];
                float2 w1 = ctw2[(c4+1)*64 + o];
                float2 w2 = ctw2[(c4+2)*64 + o];
                float2 w3 = ctw2[(c4+3)*64 + o];
                float4 r[5];
                r[0] = (pg == 0) ? *(const float4*)&gprevs[c4]
                                 : *(const float4*)&gdec[(pg*4 - 1) * 132 + c4];
                #pragma unroll
                for (int j = 0; j < 4; ++j)
                    r[j+1] = *(const float4*)&gdec[(pg*4 + j) * 132 + c4];
                #pragma unroll
                for (int i = 0; i < 4; ++i) {
                    acc4[i] += r[i+1].x*w0.x + r[i].x*w0.y
                             + r[i+1].y*w1.x + r[i].y*w1.y
                             + r[i+1].z*w2.x + r[i].z*w2.y
                             + r[i+1].w*w3.x + r[i].w*w3.y;
                }
            }
            #pragma unroll
            for (int i = 0; i < 4; ++i) {
                const int tl = pg * 4 + i;
                const int oi = cbase + o * 32768 + (l0 + tl) * PSTRIDE;
                out[oi] = acc4[i] + bias + sxr[o][tl];
            }
        }
        __syncthreads();
        if (tid < 128) gprevs[tid] = gdec[31 * 132 + tid];
    }
}

extern "C" void kernel_launch(void* const* d_in, const int* in_sizes, int n_in,
                              void* d_out, int out_size, void* d_ws, size_t ws_size,
                              hipStream_t stream)
{
    const float* x = (const float*)d_in[0];
    float* y = (float*)d_ws;     // intra output: 4*64*256*128 fp32
    float* z = (float*)d_out;

    gla_pass<128, 1><<<dim3(1024), dim3(512), 0, stream>>>(
        x, y,
        (const float*)d_in[2],  (const float*)d_in[3],  (const float*)d_in[4],
        (const float*)d_in[5],  (const float*)d_in[6],  (const float*)d_in[7],
        (const float*)d_in[8],  (const float*)d_in[9],  (const float*)d_in[10],
        (const float*)d_in[11], (const float*)d_in[12], (const float*)d_in[13]);

    gla_pass<256, 128><<<dim3(512), dim3(512), 0, stream>>>(
        y, z,
        (const float*)d_in[14], (const float*)d_in[15], (const float*)d_in[16],
        (const float*)d_in[17], (const float*)d_in[18], (const float*)d_in[19],
        (const float*)d_in[20], (const float*)d_in[21], (const float*)d_in[22],
        (const float*)d_in[23], (const float*)d_in[24], (const float*)d_in[25]);
}

// Round 5
// 5952.750 us; speedup vs baseline: 1.0743x; 1.0743x over previous
//
#include <hip/hip_runtime.h>

#define EPS 1e-5f

__device__ __forceinline__ float logsig(float z) {
    return fminf(z, 0.0f) - log1pf(__expf(-fabsf(z)));
}

// Weight pre-pack (per launch): interleave the 2-row weight pairs per column so
// the hot projection loops issue ONE float4/float2 load per cc instead of 4/2
// scalar dwords. Layout per pass (float offsets from pack base):
//   [0,     65536)  pWqk[cc*256+d] = {Wq[2cc][d], Wq[2cc+1][d], Wk[2cc][d], Wk[2cc+1][d]}
//   [65536,131072)  pWvr[cc*256+d] = {Wv[2cc][d], Wv[2cc+1][d], Wr[2cc][d], Wr[2cc+1][d]}
//   [131072,135168) pWg1[cc*32+m]  = {Wg1[2cc][m], Wg1[2cc+1][m]}
__global__ __launch_bounds__(256)
void pack_weights(const float* __restrict__ Wq0, const float* __restrict__ Wk0,
                  const float* __restrict__ Wv0, const float* __restrict__ Wr0,
                  const float* __restrict__ Wg10,
                  const float* __restrict__ Wq1, const float* __restrict__ Wk1,
                  const float* __restrict__ Wv1, const float* __restrict__ Wr1,
                  const float* __restrict__ Wg11,
                  float* __restrict__ pk)
{
    int idx = blockIdx.x * 256 + threadIdx.x;      // [0, 69632)
    int p   = (idx >= 34816) ? 1 : 0;
    int j   = idx - p * 34816;                     // 16384 + 16384 + 2048
    const float* Wq  = p ? Wq1  : Wq0;
    const float* Wk  = p ? Wk1  : Wk0;
    const float* Wv  = p ? Wv1  : Wv0;
    const float* Wr  = p ? Wr1  : Wr0;
    const float* Wg1 = p ? Wg11 : Wg10;
    float* base = pk + p * 135168;
    if (j < 16384) {
        int cc = j >> 8, d = j & 255;
        float4 v = { Wq[(2*cc)*256 + d], Wq[(2*cc+1)*256 + d],
                     Wk[(2*cc)*256 + d], Wk[(2*cc+1)*256 + d] };
        ((float4*)base)[j] = v;
    } else if (j < 32768) {
        int jj = j - 16384;
        int cc = jj >> 8, d = jj & 255;
        float4 v = { Wv[(2*cc)*256 + d], Wv[(2*cc+1)*256 + d],
                     Wr[(2*cc)*256 + d], Wr[(2*cc+1)*256 + d] };
        ((float4*)(base + 65536))[jj] = v;
    } else {
        int jj = j - 32768;
        int cc = jj >> 5, m = jj & 31;
        float2 v = { Wg1[(2*cc)*32 + m], Wg1[(2*cc+1)*32 + m] };
        ((float2*)(base + 131072))[jj] = v;
    }
}

// One block = one sequence. 512 threads = 8 waves.
// Head h = wave&3; k-half kh = wave>>2 (kh0 holds S rows 0..31, kh1 rows 32..63).
// PSTRIDE==1: intra (SLEN=128); PSTRIDE==128: inter (SLEN=256)
// Empirical RA law (R0/R1/R2): VGPR cap = 2048/(2*waves_per_wg) regardless of
// LDS/attributes -> 512 thr = 128 regs is the sweet spot; 1024 thr = 64 (spills).
// R3: slab double-buffer + reg prefetch, wave-parallel LN, Ats/gdec overlay.
// R4 post-mortem: V+R fusion kept ar[16] live across F -> spill (FETCH/WRITE
// +250MB symmetric). Reverted; kept deferred gate exps.
// R5: packed weights (1 float4/cc in C1; float4 shared by C2/G; float2 in p1)
// + explicit next-cc weight prefetch + B1 bank-conflict fix (stride-36 rows
// read 8-way conflicted; 2x32-lane column scheme is 2-way = free).
template<int SLEN, int PSTRIDE>
__global__ __launch_bounds__(512)
__attribute__((amdgpu_waves_per_eu(2, 2)))
void gla_pass(const float* __restrict__ src, float* __restrict__ out,
              const float* __restrict__ gamma, const float* __restrict__ beta,
              const float4* __restrict__ pWqk, const float4* __restrict__ pWvr,
              const float2* __restrict__ pWg1,
              const float* __restrict__ Wg2,
              const float* __restrict__ gn, const float* __restrict__ Wo,
              const float* __restrict__ ctw, const float* __restrict__ ctb)
{
    constexpr int NC = SLEN / 32;
    constexpr int L  = SLEN - 1;

    __shared__ __align__(16) float sxA[64][36];   // slab buffer A (33 cols used)
    __shared__ __align__(16) float sxB[64][36];   // slab buffer B
    __shared__ __align__(16) float sxr[64][32];   // raw slab (residual source)
    __shared__ __align__(16) float qf[32][256];   // q*Dk^-0.5 * exp(gc)
    __shared__ __align__(16) float kf[32][256];   // k * exp(-gc)
    __shared__ __align__(16) float voc[32][256];  // v -> oe1 partial -> o -> o*silu(r)
    __shared__ __align__(16) float uni[4608];     // Ats[4][32][36] OVERLAID with gdec[32][132]
    __shared__ __align__(16) float fw1t[32][36];  // (f @ Wg1)^T : fw1t[m][t]
    __shared__ __align__(16) float gprevs[128];   // deconv carry row
    __shared__ float egl[256];                    // exp(chunk-total gate)
    __shared__ float sgam[64], sbet[64];
    __shared__ float smu[33], sinv[33];
    __shared__ float gcarry[256];                 // gate cumsum carry (t=0..15 total)

    float* const Ats  = uni;          // h*1152 + t*36 + s      (live F1 -> F2b)
    float* const gdec = uni;          // row*132 + c            (live H -> I; Ats dead)

    const int tid  = threadIdx.x;
    const int lane = tid & 63;
    const int wv   = tid >> 6;        // 0..7
    const int h    = wv & 3;          // head
    const int kh   = wv >> 2;         // k-half
    const int d    = tid & 255;       // column for t-split stages
    const int th   = (tid >> 8) & 1;  // t-half (rows th*16 .. th*16+15); th == kh
    const int n    = blockIdx.x;

    int b, fixedoff;
    if constexpr (PSTRIDE == 1) { b = n >> 8; fixedoff = (n & 255) * 128; }
    else                        { b = n >> 7; fixedoff = (n & 127); }
    const int cbase = (b * 64) * 32768 + fixedoff;

    if (tid < 64)  { sgam[tid] = gamma[tid]; sbet[tid] = beta[tid]; }
    if (tid < 128) gprevs[tid] = 0.0f;

    float S[32];
    #pragma unroll
    for (int k = 0; k < 32; ++k) S[k] = 0.0f;

    const float gnv  = gn[h * 64 + lane];
    const float bias = ctb[lane];

    // ---- prologue: chunk-0 slab -> sxA (raw) ----
    #pragma unroll
    for (int k = 0; k < 5; ++k) {
        int idx = tid + k * 512;
        if (idx < 64 * 33) {
            int cc = idx / 33, i = idx - cc * 33;
            sxA[cc][i] = src[cbase + cc * 32768 + i * PSTRIDE];
        }
    }

    for (int ch = 0; ch < NC; ++ch) {
        const int l0 = ch * 32;
        float (* const cur)[36] = (ch & 1) ? sxB : sxA;
        float (* const nxt)[36] = (ch & 1) ? sxA : sxB;
        __syncthreads();              // cur(ch) raw ready (prologue or prefetch)

        // ---- A': issue next-chunk slab loads into registers (write to nxt later) ----
        float pre[5];
        const bool pf = (ch + 1 < NC);
        if (pf) {
            const int l0n = l0 + 32;
            #pragma unroll
            for (int k = 0; k < 5; ++k) {
                int idx = tid + k * 512;
                if (idx < 64 * 33) {
                    int cc = idx / 33, i = idx - cc * 33;
                    int p  = l0n + i; if (p > SLEN - 1) p = SLEN - 1;
                    pre[k] = src[cbase + cc * 32768 + p * PSTRIDE];
                }
            }
        }

        // ---- B1: per-column LN stats; 2 cols/wave, 32 lanes each (2-way bank = free) ----
        for (int cp = wv; cp < 17; cp += 8) {
            const int col = 2 * cp + (lane >> 5);
            float s1 = 0.0f, s2 = 0.0f;
            if (col < 33) {
                const int c0 = (lane & 31) * 2;
                float x0 = cur[c0][col], x1 = cur[c0 + 1][col];
                s1 = x0 + x1; s2 = x0 * x0 + x1 * x1;
            }
            #pragma unroll
            for (int off = 16; off > 0; off >>= 1) {
                s1 += __shfl_xor(s1, off, 64);
                s2 += __shfl_xor(s2, off, 64);
            }
            if ((lane & 31) == 0 && col < 33) {
                float mu  = s1 * (1.0f / 64.0f);
                float var = s2 * (1.0f / 64.0f) - mu * mu;
                smu[col]  = mu;
                sinv[col] = rsqrtf(fmaxf(var, 0.0f) + EPS);
            }
        }
        __syncthreads();

        // ---- B2: normalize in place, raw copy to sxr fused ----
        #pragma unroll
        for (int k = 0; k < 5; ++k) {
            int idx = tid + k * 512;
            if (idx < 64 * 33) {
                int cc = idx / 33, i = idx - cc * 33;
                float x = cur[cc][i];
                if (i < 32) sxr[cc][i] = x;
                cur[cc][i] = (x - smu[i]) * sinv[i] * sgam[cc] + sbet[cc];
            }
        }
        __syncthreads();

        // ---- gate p1: fw1t[m][t] (packed float2 weights) ----
        {
            const int m = tid & 31, tg2 = tid >> 5;   // tg2 in [0,16)
            float a0 = 0.0f, a1 = 0.0f;
            float2 wg = pWg1[m];
            #pragma unroll 2
            for (int cc = 0; cc < 64; ++cc) {
                float2 wn = pWg1[((cc + 1) & 63) * 32 + m];
                a0 += cur[cc][tg2]      * wg.x + cur[cc][tg2 + 1]  * wg.y;
                a1 += cur[cc][tg2 + 16] * wg.x + cur[cc][tg2 + 17] * wg.y;
                wg = wn;
            }
            fw1t[m][tg2] = a0; fw1t[m][tg2 + 16] = a1;
        }
        __syncthreads();

        // ---- gate p2: per (col d, t-half) cumsum with carry -> rn[16] ----
        float rn[16];                 // log-gate cumsum; exps deferred to stores
        {
            const int t0 = th * 16;
            float acc2[16];
            #pragma unroll
            for (int t = 0; t < 16; ++t) acc2[t] = 0.0f;
            for (int mm = 0; mm < 32; ++mm) {
                const float w = Wg2[mm * 256 + d];
                #pragma unroll
                for (int i = 0; i < 4; ++i) {
                    float4 f4 = *(const float4*)&fw1t[mm][t0 + 4 * i];
                    acc2[4*i+0] += f4.x * w; acc2[4*i+1] += f4.y * w;
                    acc2[4*i+2] += f4.z * w; acc2[4*i+3] += f4.w * w;
                }
            }
            float r = 0.0f;
            #pragma unroll
            for (int t = 0; t < 16; ++t) {
                if ((l0 + t0 + t) < L) r += logsig(acc2[t]) * (1.0f / 32.0f);
                acc2[t] = r;                    // reuse as cumsum store
            }
            if (th == 0) gcarry[d] = r;
            __syncthreads();
            const float c = (th == 0) ? 0.0f : gcarry[d];
            #pragma unroll
            for (int t = 0; t < 16; ++t) rn[t] = c + acc2[t];
            if (th == 1) egl[d] = __expf(rn[15]);
        }

        // ---- A'': write prefetched slab into nxt ----
        if (pf) {
            #pragma unroll
            for (int k = 0; k < 5; ++k) {
                int idx = tid + k * 512;
                if (idx < 64 * 33) {
                    int cc = idx / 33, i = idx - cc * 33;
                    nxt[cc][i] = pre[k];
                }
            }
        }

        // ---- C1: q,k fused projection (packed float4 weights, next-cc prefetch) ----
        {
            const int t0 = th * 16;
            float aq[16], ak[16];
            #pragma unroll
            for (int t = 0; t < 16; ++t) { aq[t] = 0.0f; ak[t] = 0.0f; }
            float4 w = pWqk[d];
            for (int cc = 0; cc < 64; ++cc) {
                float4 wn = pWqk[((cc + 1) & 63) * 256 + d];
                float col[17];
                #pragma unroll
                for (int i = 0; i < 4; ++i) {
                    float4 c4 = *(const float4*)&cur[cc][t0 + 4 * i];
                    col[4*i] = c4.x; col[4*i+1] = c4.y; col[4*i+2] = c4.z; col[4*i+3] = c4.w;
                }
                col[16] = cur[cc][t0 + 16];
                #pragma unroll
                for (int t = 0; t < 16; ++t) {
                    aq[t] += col[t] * w.x + col[t+1] * w.y;
                    ak[t] += col[t] * w.z + col[t+1] * w.w;
                }
                w = wn;
            }
            #pragma unroll
            for (int t = 0; t < 16; ++t) {
                bool valid = (l0 + t0 + t) < L;
                qf[t0 + t][d] = valid ? aq[t] * 0.125f * __expf(rn[t]) : 0.0f;
                kf[t0 + t][d] = valid ? ak[t] * __expf(-rn[t]) : 0.0f;
            }
        }
        // ---- C2: v projection (packed .x/.y) ----
        {
            const int t0 = th * 16;
            float av[16];
            #pragma unroll
            for (int t = 0; t < 16; ++t) av[t] = 0.0f;
            float4 w = pWvr[d];
            for (int cc = 0; cc < 64; ++cc) {
                float4 wn = pWvr[((cc + 1) & 63) * 256 + d];
                float col[17];
                #pragma unroll
                for (int i = 0; i < 4; ++i) {
                    float4 c4 = *(const float4*)&cur[cc][t0 + 4 * i];
                    col[4*i] = c4.x; col[4*i+1] = c4.y; col[4*i+2] = c4.z; col[4*i+3] = c4.w;
                }
                col[16] = cur[cc][t0 + 16];
                #pragma unroll
                for (int t = 0; t < 16; ++t) av[t] += col[t] * w.x + col[t+1] * w.y;
                w = wn;
            }
            #pragma unroll
            for (int t = 0; t < 16; ++t)
                voc[t0 + t][d] = ((l0 + t0 + t) < L) ? av[t] : 0.0f;
        }
        __syncthreads();

        // ---- F: attention; 2 waves per head ----
        const int base = h * 64;
        float vcol[32];
        #pragma unroll
        for (int t = 0; t < 32; ++t) vcol[t] = voc[t][base + lane];

        // F1: triangular scores, 128 lanes per head
        for (int pi = lane + 64 * kh; pi < 528; pi += 128) {
            float fpi = (float)pi;
            int t = (int)((sqrtf(8.0f * fpi + 1.0f) - 1.0f) * 0.5f);
            if (((t + 1) * (t + 2)) / 2 <= pi) ++t;
            if ((t * (t + 1)) / 2 > pi) --t;
            int s = pi - (t * (t + 1)) / 2;
            float a = 0.0f;
            #pragma unroll
            for (int ii = 0; ii < 16; ++ii) {
                int i = (ii + lane) & 15;
                float4 q4 = *(const float4*)&qf[t][base + 4 * i];
                float4 k4 = *(const float4*)&kf[s][base + 4 * i];
                a += q4.x*k4.x + q4.y*k4.y + q4.z*k4.z + q4.w*k4.w;
            }
            Ats[h * 1152 + t * 36 + s] = a;
        }
        __syncthreads();   // A: Ats ready; all vcol snapshots done (voc dead as v)

        // F2a: kh1 writes o_inter partial (vs pre-update S rows 32..63) into voc
        if (kh == 1) {
            #pragma unroll
            for (int t = 0; t < 32; ++t) {
                float oe = 0.0f;
                #pragma unroll
                for (int i = 0; i < 8; ++i) {
                    float4 q4 = *(const float4*)&qf[t][base + 32 + 4 * i];
                    oe += q4.x*S[4*i] + q4.y*S[4*i+1] + q4.z*S[4*i+2] + q4.w*S[4*i+3];
                }
                voc[t][base + lane] = oe;
            }
        }
        __syncthreads();   // B: oe1 partials in voc

        if (kh == 0) {
            // F2b: o = oe0 + oe1 + o_intra, RMS-norm, final o into voc
            #pragma unroll
            for (int t = 0; t < 32; ++t) {
                float ot = voc[t][base + lane];
                #pragma unroll
                for (int i = 0; i < 8; ++i) {
                    float4 q4 = *(const float4*)&qf[t][base + 4 * i];
                    ot += q4.x*S[4*i] + q4.y*S[4*i+1] + q4.z*S[4*i+2] + q4.w*S[4*i+3];
                }
                const float* arow = &Ats[h * 1152 + t * 36];
                #pragma unroll
                for (int s4 = 0; s4 + 4 <= t + 1; s4 += 4) {
                    float4 a4 = *(const float4*)&arow[s4];
                    ot += a4.x*vcol[s4] + a4.y*vcol[s4+1] + a4.z*vcol[s4+2] + a4.w*vcol[s4+3];
                }
                #pragma unroll
                for (int s = (t + 1) & ~3; s <= t; ++s) ot += arow[s] * vcol[s];
                float ss = ot * ot;
                #pragma unroll
                for (int off = 32; off > 0; off >>= 1) ss += __shfl_xor(ss, off, 64);
                voc[t][base + lane] = ot * rsqrtf(ss * (1.0f / 64.0f) + EPS) * gnv;
            }
        } else {
            // kh1: F4 state update rows 32..63 (overlaps kh0's F2b)
            const int kb = base + 32;
            #pragma unroll
            for (int i = 0; i < 8; ++i) {
                float s0 = 0.0f, s1 = 0.0f, s2 = 0.0f, s3 = 0.0f;
                #pragma unroll
                for (int t = 0; t < 32; ++t) {
                    float4 k4 = *(const float4*)&kf[t][kb + 4 * i];
                    const float vt = vcol[t];
                    s0 += k4.x * vt; s1 += k4.y * vt; s2 += k4.z * vt; s3 += k4.w * vt;
                }
                S[4*i+0] = egl[kb + 4*i+0] * (S[4*i+0] + s0);
                S[4*i+1] = egl[kb + 4*i+1] * (S[4*i+1] + s1);
                S[4*i+2] = egl[kb + 4*i+2] * (S[4*i+2] + s2);
                S[4*i+3] = egl[kb + 4*i+3] * (S[4*i+3] + s3);
            }
        }
        __syncthreads();   // C: final o in voc; kh0 may now update S

        if (kh == 0) {
            // F4 state update rows 0..31 (overlaps kh1's half of G)
            const int kb = base;
            #pragma unroll
            for (int i = 0; i < 8; ++i) {
                float s0 = 0.0f, s1 = 0.0f, s2 = 0.0f, s3 = 0.0f;
                #pragma unroll
                for (int t = 0; t < 32; ++t) {
                    float4 k4 = *(const float4*)&kf[t][kb + 4 * i];
                    const float vt = vcol[t];
                    s0 += k4.x * vt; s1 += k4.y * vt; s2 += k4.z * vt; s3 += k4.w * vt;
                }
                S[4*i+0] = egl[kb + 4*i+0] * (S[4*i+0] + s0);
                S[4*i+1] = egl[kb + 4*i+1] * (S[4*i+1] + s1);
                S[4*i+2] = egl[kb + 4*i+2] * (S[4*i+2] + s2);
                S[4*i+3] = egl[kb + 4*i+3] * (S[4*i+3] + s3);
            }
        }

        // ---- G: r = f @ Wr (packed .z/.w) ; voc *= silu(r) ----
        {
            const int t0 = th * 16;
            float ar[16];
            #pragma unroll
            for (int t = 0; t < 16; ++t) ar[t] = 0.0f;
            float4 w = pWvr[d];
            for (int cc = 0; cc < 64; ++cc) {
                float4 wn = pWvr[((cc + 1) & 63) * 256 + d];
                float col[17];
                #pragma unroll
                for (int i = 0; i < 4; ++i) {
                    float4 c4 = *(const float4*)&cur[cc][t0 + 4 * i];
                    col[4*i] = c4.x; col[4*i+1] = c4.y; col[4*i+2] = c4.z; col[4*i+3] = c4.w;
                }
                col[16] = cur[cc][t0 + 16];
                #pragma unroll
                for (int t = 0; t < 16; ++t) ar[t] += col[t] * w.z + col[t+1] * w.w;
                w = wn;
            }
            #pragma unroll
            for (int t = 0; t < 16; ++t) {
                const float r = ar[t];
                voc[t0 + t][d] *= r / (1.0f + __expf(-r));
            }
        }
        __syncthreads();

        // ---- H: gdec = oc @ Wo ; thread = (m2 in [0,64), 2 cols, 4 rows) ----
        {
            const int m2  = tid & 63;
            const int tg4 = tid >> 6;        // 0..7 -> rows tg4*4..+3
            float accA[4] = {0,0,0,0}, accB[4] = {0,0,0,0};
            for (int j = 0; j < 256; j += 4) {
                float wA0 = Wo[(j+0)*128 + m2],      wB0 = Wo[(j+0)*128 + m2 + 64];
                float wA1 = Wo[(j+1)*128 + m2],      wB1 = Wo[(j+1)*128 + m2 + 64];
                float wA2 = Wo[(j+2)*128 + m2],      wB2 = Wo[(j+2)*128 + m2 + 64];
                float wA3 = Wo[(j+3)*128 + m2],      wB3 = Wo[(j+3)*128 + m2 + 64];
                #pragma unroll
                for (int i = 0; i < 4; ++i) {
                    float4 o4 = *(const float4*)&voc[tg4 * 4 + i][j];
                    accA[i] += o4.x*wA0 + o4.y*wA1 + o4.z*wA2 + o4.w*wA3;
                    accB[i] += o4.x*wB0 + o4.y*wB1 + o4.z*wB2 + o4.w*wB3;
                }
            }
            #pragma unroll
            for (int i = 0; i < 4; ++i) {
                gdec[(tg4 * 4 + i) * 132 + m2]      = accA[i];
                gdec[(tg4 * 4 + i) * 132 + m2 + 64] = accB[i];
            }
        }
        __syncthreads();

        // ---- I: deconv1d (K=2) + bias + residual (from sxr) + store ----
        {
            const int o  = lane;
            const int pg = wv;               // 0..7 -> rows pg*4..+3
            const float2* ctw2 = (const float2*)ctw;   // [cin][o] -> (w_k0, w_k1)
            float acc4[4] = {0,0,0,0};
            for (int c4 = 0; c4 < 128; c4 += 4) {
                float2 w0 = ctw2[(c4+0)*64 + o];
                float2 w1 = ctw2[(c4+1)*64 + o];
                float2 w2 = ctw2[(c4+2)*64 + o];
                float2 w3 = ctw2[(c4+3)*64 + o];
                float4 r[5];
                r[0] = (pg == 0) ? *(const float4*)&gprevs[c4]
                                 : *(const float4*)&gdec[(pg*4 - 1) * 132 + c4];
                #pragma unroll
                for (int j = 0; j < 4; ++j)
                    r[j+1] = *(const float4*)&gdec[(pg*4 + j) * 132 + c4];
                #pragma unroll
                for (int i = 0; i < 4; ++i) {
                    acc4[i] += r[i+1].x*w0.x + r[i].x*w0.y
                             + r[i+1].y*w1.x + r[i].y*w1.y
                             + r[i+1].z*w2.x + r[i].z*w2.y
                             + r[i+1].w*w3.x + r[i].w*w3.y;
                }
            }
            #pragma unroll
            for (int i = 0; i < 4; ++i) {
                const int tl = pg * 4 + i;
                const int oi = cbase + o * 32768 + (l0 + tl) * PSTRIDE;
                out[oi] = acc4[i] + bias + sxr[o][tl];
            }
        }
        __syncthreads();
        if (tid < 128) gprevs[tid] = gdec[31 * 132 + tid];
    }
}

extern "C" void kernel_launch(void* const* d_in, const int* in_sizes, int n_in,
                              void* d_out, int out_size, void* d_ws, size_t ws_size,
                              hipStream_t stream)
{
    const float* x = (const float*)d_in[0];
    float* y  = (float*)d_ws;               // intra output: 4*64*256*128 fp32
    float* pk = (float*)d_ws + 8388608;     // packed weights, 2 passes x 135168 floats
    float* z  = (float*)d_out;

    pack_weights<<<dim3(272), dim3(256), 0, stream>>>(
        (const float*)d_in[4],  (const float*)d_in[5],  (const float*)d_in[6],
        (const float*)d_in[9],  (const float*)d_in[7],
        (const float*)d_in[16], (const float*)d_in[17], (const float*)d_in[18],
        (const float*)d_in[21], (const float*)d_in[19],
        pk);

    gla_pass<128, 1><<<dim3(1024), dim3(512), 0, stream>>>(
        x, y,
        (const float*)d_in[2],  (const float*)d_in[3],
        (const float4*)pk, (const float4*)(pk + 65536), (const float2*)(pk + 131072),
        (const float*)d_in[8],
        (const float*)d_in[10], (const float*)d_in[11],
        (const float*)d_in[12], (const float*)d_in[13]);

    gla_pass<256, 128><<<dim3(512), dim3(512), 0, stream>>>(
        y, z,
        (const float*)d_in[14], (const float*)d_in[15],
        (const float4*)(pk + 135168), (const float4*)(pk + 135168 + 65536),
        (const float2*)(pk + 135168 + 131072),
        (const float*)d_in[20],
        (const float*)d_in[22], (const float*)d_in[23],
        (const float*)d_in[24], (const float*)d_in[25]);
}